// Round 7
// baseline (187.790 us; speedup 1.0000x reference)
//
#include <hip/hip_runtime.h>
#include <stdint.h>

#define D_DIM 768
#define KNEG 100
#define INV_KAPPA 10.0f
#define FP8_SCALE 16.0f

typedef float floatx2 __attribute__((ext_vector_type(2)));

// ---------------- threefry2x32 (exact JAX semantics) ----------------
__device__ __forceinline__ uint32_t rotl32(uint32_t x, int r) {
  return (x << r) | (x >> (32 - r));
}

#define TF_R4(a, b, c, d)                        \
  x0 += x1; x1 = rotl32(x1, a); x1 ^= x0;        \
  x0 += x1; x1 = rotl32(x1, b); x1 ^= x0;        \
  x0 += x1; x1 = rotl32(x1, c); x1 ^= x0;        \
  x0 += x1; x1 = rotl32(x1, d); x1 ^= x0;

__device__ __forceinline__ void threefry2x32(uint32_t ks0, uint32_t ks1,
                                             uint32_t x0, uint32_t x1,
                                             uint32_t& o0, uint32_t& o1) {
  uint32_t ks2 = ks0 ^ ks1 ^ 0x1BD11BDAu;
  x0 += ks0; x1 += ks1;
  TF_R4(13, 15, 26, 6)   x0 += ks1; x1 += ks2 + 1u;
  TF_R4(17, 29, 16, 24)  x0 += ks2; x1 += ks0 + 2u;
  TF_R4(13, 15, 26, 6)   x0 += ks0; x1 += ks1 + 3u;
  TF_R4(17, 29, 16, 24)  x0 += ks1; x1 += ks2 + 4u;
  TF_R4(13, 15, 26, 6)   x0 += ks2; x1 += ks0 + 5u;
  o0 = x0; o1 = x1;
}

__device__ __forceinline__ int sample_negative(int row, int k, int N) {
  // replicate jax.random.randint(key(42), (N,100), 0, N-1) element (row,k)
  uint32_t a0, b0, a1, b1;
  threefry2x32(0u, 42u, 0u, 2u, a0, b0);   // constant-folds at -O3
  threefry2x32(0u, 42u, 1u, 3u, a1, b1);
  uint32_t total = (uint32_t)N * KNEG;
  uint32_t half = total >> 1;
  uint32_t j = (uint32_t)row * KNEG + (uint32_t)k;
  uint32_t x0 = (j < half) ? j : (j - half);
  uint32_t x1 = (j < half) ? (j + half) : j;
  uint32_t h0, h1, l0, l1;
  threefry2x32(a0, a1, x0, x1, h0, h1);
  threefry2x32(b0, b1, x0, x1, l0, l1);
  uint32_t hb = (j < half) ? h0 : h1;
  uint32_t lb = (j < half) ? l0 : l1;
  uint32_t span = (uint32_t)(N - 1);
  uint32_t mult = 65536u % span;
  mult = (mult * mult) % span;
  uint32_t off = ((hb % span) * mult + (lb % span)) % span;
  int idx = (int)off;
  if (idx >= row) idx++;  // skip self
  return idx;
}

// ---------------- fp8 encode/decode + packed f32 math (inline asm) ----------------
__device__ __forceinline__ uint32_t enc_fp8x2(float a, float b) {
  uint32_t r;
  asm volatile("v_cvt_pk_fp8_f32 %0, %1, %2" : "=v"(r) : "v"(a), "v"(b));
  return r;  // valid fp8 pair in [15:0]
}
__device__ __forceinline__ uint32_t enc_fp8x4(float a, float b, float c, float d) {
  uint32_t lo = enc_fp8x2(a, b);
  uint32_t hi = enc_fp8x2(c, d);
  return (lo & 0xFFFFu) | (hi << 16);
}
__device__ __forceinline__ floatx2 dec_fp8x2(uint32_t w) {
  floatx2 p;
  asm("v_cvt_pk_f32_fp8 %0, %1" : "=v"(p) : "v"(w));  // decodes bytes [1:0]
  return p;
}
__device__ __forceinline__ floatx2 pk_mul(floatx2 a, floatx2 b) {
  floatx2 d;
  asm("v_pk_mul_f32 %0, %1, %2" : "=v"(d) : "v"(a), "v"(b));
  return d;
}
__device__ __forceinline__ floatx2 pk_fma(floatx2 a, floatx2 b, floatx2 c) {
  floatx2 d;
  asm("v_pk_fma_f32 %0, %1, %2, %3" : "=v"(d) : "v"(a), "v"(b), "v"(c));
  return d;
}

// ---------------- reciprocal L2 norms (fallback path only) ----------------
__global__ __launch_bounds__(256) void rnorm_kernel(const float* __restrict__ x,
                                                    float* __restrict__ rn,
                                                    int nrows) {
  int wave = threadIdx.x >> 6;
  int lane = threadIdx.x & 63;
  int row = blockIdx.x * 4 + wave;
  if (row >= nrows) return;
  const float4* p = (const float4*)(x + (size_t)row * D_DIM);
  float s = 0.f;
#pragma unroll
  for (int q = 0; q < 3; ++q) {
    float4 v = p[lane + 64 * q];
    s += v.x * v.x + v.y * v.y + v.z * v.z + v.w * v.w;
  }
#pragma unroll
  for (int o = 32; o; o >>= 1) s += __shfl_xor(s, o);
  if (lane == 0) rn[row] = 1.0f / fmaxf(sqrtf(s), 1e-8f);
}

// ---------------- normalize labels -> fp8 table (x16), row = 192 dwords ----------------
__global__ __launch_bounds__(256) void prep_fp8_kernel(const float* __restrict__ lbl,
                                                       uint32_t* __restrict__ tab,
                                                       uint32_t* __restrict__ counter,
                                                       int nrows) {
  if (blockIdx.x == 0 && threadIdx.x == 0) *counter = 0;  // re-zero ticket each call
  int wave = threadIdx.x >> 6;
  int lane = threadIdx.x & 63;
  int row = blockIdx.x * 4 + wave;
  if (row >= nrows) return;
  // element ownership mirrors the contrast kernel's target layout:
  //   elems 8L..8L+7 -> float4 [2L],[2L+1];  elems 512+4L..+3 -> float4 [128+L]
  const float4* p = (const float4*)(lbl + (size_t)row * D_DIM);
  float4 v0 = p[2 * lane], v1 = p[2 * lane + 1], v2 = p[128 + lane];
  float s = v0.x * v0.x + v0.y * v0.y + v0.z * v0.z + v0.w * v0.w +
            v1.x * v1.x + v1.y * v1.y + v1.z * v1.z + v1.w * v1.w +
            v2.x * v2.x + v2.y * v2.y + v2.z * v2.z + v2.w * v2.w;
#pragma unroll
  for (int o = 32; o; o >>= 1) s += __shfl_xor(s, o);
  float r = FP8_SCALE / fmaxf(sqrtf(s), 1e-8f);
  uint32_t d0 = enc_fp8x4(v0.x * r, v0.y * r, v0.z * r, v0.w * r);
  uint32_t d1 = enc_fp8x4(v1.x * r, v1.y * r, v1.z * r, v1.w * r);
  uint32_t d2 = enc_fp8x4(v2.x * r, v2.y * r, v2.z * r, v2.w * r);
  uint32_t* tp = tab + (size_t)row * (D_DIM / 4);
  ((uint2*)tp)[lane] = make_uint2(d0, d1);  // dwords 2L, 2L+1
  tp[128 + lane] = d2;                      // dword 128+L
}

// per-candidate fragment dot via packed-f32: 6 dec + 3 shr + 1 pk_mul + 5 pk_fma + 1 add
__device__ __forceinline__ float dot12_fp8(const floatx2 T[6], uint2 u, uint32_t w) {
  floatx2 acc = pk_mul(dec_fp8x2(u.x), T[0]);
  acc = pk_fma(dec_fp8x2(u.x >> 16), T[1], acc);
  acc = pk_fma(dec_fp8x2(u.y), T[2], acc);
  acc = pk_fma(dec_fp8x2(u.y >> 16), T[3], acc);
  acc = pk_fma(dec_fp8x2(w), T[4], acc);
  acc = pk_fma(dec_fp8x2(w >> 16), T[5], acc);
  return acc.x + acc.y;
}

__device__ __forceinline__ void load_b8(const uint32_t* __restrict__ tab,
                                        const int* cand, int base, int lane,
                                        uint2 u[8], uint32_t w[8]) {
#pragma unroll
  for (int i = 0; i < 8; ++i) {
    const uint32_t* p = tab + (size_t)cand[base + i] * (D_DIM / 4);
    u[i] = ((const uint2*)p)[lane];
    w[i] = p[128 + lane];
  }
}

__device__ __forceinline__ void dots_b8(const floatx2 T[6], const uint2 u[8],
                                        const uint32_t w[8], float s[8]) {
#pragma unroll
  for (int i = 0; i < 8; ++i) s[i] = dot12_fp8(T, u[i], w[i]);
}

// 8-value butterfly: 10 shuffles reduce 8 wave-wide accumulators;
// lane l<8 ends holding the total of accumulator l.
__device__ __forceinline__ void reduce8_store(const float s[8], float* sims,
                                              int base, int lane) {
  float x01 = (lane & 1) ? s[1] : s[0];
  float y01 = (lane & 1) ? s[0] : s[1];
  x01 += __shfl_xor(y01, 1);
  float x23 = (lane & 1) ? s[3] : s[2];
  float y23 = (lane & 1) ? s[2] : s[3];
  x23 += __shfl_xor(y23, 1);
  float x45 = (lane & 1) ? s[5] : s[4];
  float y45 = (lane & 1) ? s[4] : s[5];
  x45 += __shfl_xor(y45, 1);
  float x67 = (lane & 1) ? s[7] : s[6];
  float y67 = (lane & 1) ? s[6] : s[7];
  x67 += __shfl_xor(y67, 1);
  float p03 = (lane & 2) ? x23 : x01;
  float q03 = (lane & 2) ? x01 : x23;
  p03 += __shfl_xor(q03, 2);
  float p47 = (lane & 2) ? x67 : x45;
  float q47 = (lane & 2) ? x45 : x67;
  p47 += __shfl_xor(q47, 2);
  float r = (lane & 4) ? p47 : p03;
  float t = (lane & 4) ? p03 : p47;
  r += __shfl_xor(t, 4);
  r += __shfl_xor(r, 8);
  r += __shfl_xor(r, 16);
  r += __shfl_xor(r, 32);
  if (lane < 8) sims[base + lane] = r;
}

// ---------------- contrastive loss + fused deterministic finalize ----------------
__global__ __launch_bounds__(256) void contrast_fp8_kernel(
    const float* __restrict__ tgt, const uint32_t* __restrict__ tab,
    const float* __restrict__ perp, float* __restrict__ rowloss,
    uint32_t* __restrict__ counter, float* __restrict__ out, int N, int GV) {
  int row = blockIdx.x;
  __shared__ int cand[104];
  __shared__ float sims[104];
  __shared__ int winner_flag;
  int tid = threadIdx.x;

  if (tid == 0) { cand[0] = row; winner_flag = 0; }
  else if (tid <= KNEG) cand[tid] = sample_negative(row, tid - 1, N);
  else if (tid < 104) cand[tid] = row;  // pad: computed, never used by logsumexp
  __syncthreads();

  int wave = tid >> 6, lane = tid & 63;
  const float4* tp = (const float4*)(tgt + (size_t)row * D_DIM);
  float4 t0 = tp[2 * lane], t1 = tp[2 * lane + 1], t2 = tp[128 + lane];
  // per-wave target sumsq (replicated across waves; kills the rnorm pass)
  float ss = t0.x * t0.x + t0.y * t0.y + t0.z * t0.z + t0.w * t0.w +
             t1.x * t1.x + t1.y * t1.y + t1.z * t1.z + t1.w * t1.w +
             t2.x * t2.x + t2.y * t2.y + t2.z * t2.z + t2.w * t2.w;
#pragma unroll
  for (int o = 32; o; o >>= 1) ss += __shfl_xor(ss, o);
  float sc = (INV_KAPPA / FP8_SCALE) / fmaxf(sqrtf(ss), 1e-8f);
  floatx2 T[6];
  T[0] = floatx2{t0.x * sc, t0.y * sc};
  T[1] = floatx2{t0.z * sc, t0.w * sc};
  T[2] = floatx2{t1.x * sc, t1.y * sc};
  T[3] = floatx2{t1.z * sc, t1.w * sc};
  T[4] = floatx2{t2.x * sc, t2.y * sc};
  T[5] = floatx2{t2.z * sc, t2.w * sc};

  // wave w owns candidates [26w, 26w+26): batches 8/8/8/2, 2-deep pipeline.
  int cb = wave * 26;
  uint2 ua[8]; uint32_t wa[8];
  uint2 ub[8]; uint32_t wb[8];
  float s[8];

  load_b8(tab, cand, cb, lane, ua, wa);          // batch 0 in flight
  load_b8(tab, cand, cb + 8, lane, ub, wb);      // batch 1 in flight
  dots_b8(T, ua, wa, s);                         // consume batch 0
  reduce8_store(s, sims, cb, lane);
  load_b8(tab, cand, cb + 16, lane, ua, wa);     // batch 2 in flight
  dots_b8(T, ub, wb, s);                         // consume batch 1
  reduce8_store(s, sims, cb + 8, lane);
  // tail (2 candidates) in flight
  uint2 ut0, ut1; uint32_t wt0, wt1;
  {
    const uint32_t* p0 = tab + (size_t)cand[cb + 24] * (D_DIM / 4);
    const uint32_t* p1 = tab + (size_t)cand[cb + 25] * (D_DIM / 4);
    ut0 = ((const uint2*)p0)[lane]; wt0 = p0[128 + lane];
    ut1 = ((const uint2*)p1)[lane]; wt1 = p1[128 + lane];
  }
  dots_b8(T, ua, wa, s);                         // consume batch 2
  reduce8_store(s, sims, cb + 16, lane);
  {                                              // consume tail
    float s0 = dot12_fp8(T, ut0, wt0);
    float s1 = dot12_fp8(T, ut1, wt1);
    float x = (lane & 1) ? s1 : s0;
    float y = (lane & 1) ? s0 : s1;
    x += __shfl_xor(y, 1);
    x += __shfl_xor(x, 2);
    x += __shfl_xor(x, 4);
    x += __shfl_xor(x, 8);
    x += __shfl_xor(x, 16);
    x += __shfl_xor(x, 32);
    if (lane < 2) sims[cb + 24 + lane] = x;
  }
  __syncthreads();

  if (wave == 0) {
    float v0 = (lane < KNEG + 1) ? sims[lane] : -INFINITY;
    float v1 = (lane + 64 < KNEG + 1) ? sims[lane + 64] : -INFINITY;
    float m = fmaxf(v0, v1);
#pragma unroll
    for (int o = 32; o; o >>= 1) m = fmaxf(m, __shfl_xor(m, o));
    float e = ((lane < KNEG + 1) ? expf(v0 - m) : 0.f) +
              ((lane + 64 < KNEG + 1) ? expf(v1 - m) : 0.f);
#pragma unroll
    for (int o = 32; o; o >>= 1) e += __shfl_xor(e, o);
    if (lane == 0) {
      float rl = m + logf(e) - sims[0];
      __hip_atomic_store(&rowloss[row], rl, __ATOMIC_RELAXED,
                         __HIP_MEMORY_SCOPE_AGENT);
      __threadfence();  // release: rowloss visible device-wide before ticket
      uint32_t old = __hip_atomic_fetch_add(counter, 1u, __ATOMIC_ACQ_REL,
                                            __HIP_MEMORY_SCOPE_AGENT);
      if (old == (uint32_t)(N - 1)) winner_flag = 1;
    }
  }
  __syncthreads();

  if (winner_flag) {  // exactly one block: deterministic final reduction
    __threadfence();  // acquire
    float sum = 0.f;
    for (int i = tid; i < N; i += 256)
      sum += __hip_atomic_load(&rowloss[i], __ATOMIC_RELAXED,
                               __HIP_MEMORY_SCOPE_AGENT);
    float dv = 0.f;
    for (int i = tid; i < GV; i += 256) {
      float p = perp[i];
      dv += p * logf(p + 1e-9f);
    }
#pragma unroll
    for (int o = 32; o; o >>= 1) {
      sum += __shfl_xor(sum, o);
      dv += __shfl_xor(dv, o);
    }
    __shared__ float fs[4], fd[4];
    if (lane == 0) { fs[wave] = sum; fd[wave] = dv; }
    __syncthreads();
    if (tid == 0) {
      float S = fs[0] + fs[1] + fs[2] + fs[3];
      float DV = fd[0] + fd[1] + fd[2] + fd[3];
      out[0] = S / (float)N + 0.1f * (-DV / (float)GV);
    }
  }
}

// ---------------- f32 fallback (tiny-ws safety; proven R0 path) ----------------
__global__ __launch_bounds__(256) void contrast_kernel(
    const float* __restrict__ tgt, const float* __restrict__ lbl,
    const float* __restrict__ rt, const float* __restrict__ rl,
    float* __restrict__ rowloss, int N) {
  int row = blockIdx.x;
  __shared__ int cand[104];
  __shared__ float sims[104];
  int tid = threadIdx.x;
  if (tid == 0) cand[0] = row;
  else if (tid <= KNEG) cand[tid] = sample_negative(row, tid - 1, N);
  __syncthreads();

  int wave = tid >> 6, lane = tid & 63;
  const float4* tp = (const float4*)(tgt + (size_t)row * D_DIM);
  float rscale = rt[row];
  float4 t0 = tp[lane], t1 = tp[lane + 64], t2 = tp[lane + 128];

  for (int c = wave; c < KNEG + 1; c += 4) {
    int ci = cand[c];
    const float4* lp = (const float4*)(lbl + (size_t)ci * D_DIM);
    float4 l0 = lp[lane], l1 = lp[lane + 64], l2 = lp[lane + 128];
    float s = t0.x * l0.x + t0.y * l0.y + t0.z * l0.z + t0.w * l0.w +
              t1.x * l1.x + t1.y * l1.y + t1.z * l1.z + t1.w * l1.w +
              t2.x * l2.x + t2.y * l2.y + t2.z * l2.z + t2.w * l2.w;
#pragma unroll
    for (int o = 32; o; o >>= 1) s += __shfl_xor(s, o);
    if (lane == 0) sims[c] = s * rscale * rl[ci] * INV_KAPPA;
  }
  __syncthreads();

  if (wave == 0) {
    float v0 = (lane < KNEG + 1) ? sims[lane] : -INFINITY;
    float v1 = (lane + 64 < KNEG + 1) ? sims[lane + 64] : -INFINITY;
    float m = fmaxf(v0, v1);
#pragma unroll
    for (int o = 32; o; o >>= 1) m = fmaxf(m, __shfl_xor(m, o));
    float e = ((lane < KNEG + 1) ? expf(v0 - m) : 0.f) +
              ((lane + 64 < KNEG + 1) ? expf(v1 - m) : 0.f);
#pragma unroll
    for (int o = 32; o; o >>= 1) e += __shfl_xor(e, o);
    if (lane == 0) rowloss[row] = m + logf(e) - sims[0];
  }
}

// ---------------- final deterministic reduction (fallback path only) ----------------
__global__ __launch_bounds__(256) void finalize_kernel(
    const float* __restrict__ rowloss, const float* __restrict__ perp,
    float* __restrict__ out, int N, int GV) {
  int tid = threadIdx.x;
  float s = 0.f;
  for (int i = tid; i < N; i += 256) s += rowloss[i];
  float dv = 0.f;
  for (int i = tid; i < GV; i += 256) {
    float p = perp[i];
    dv += p * logf(p + 1e-9f);
  }
#pragma unroll
  for (int o = 32; o; o >>= 1) {
    s += __shfl_xor(s, o);
    dv += __shfl_xor(dv, o);
  }
  __shared__ float ss[4], sd[4];
  if ((tid & 63) == 0) { ss[tid >> 6] = s; sd[tid >> 6] = dv; }
  __syncthreads();
  if (tid == 0) {
    float S = ss[0] + ss[1] + ss[2] + ss[3];
    float DV = sd[0] + sd[1] + sd[2] + sd[3];
    out[0] = S / (float)N + 0.1f * (-DV / (float)GV);
  }
}

extern "C" void kernel_launch(void* const* d_in, const int* in_sizes, int n_in,
                              void* d_out, int out_size, void* d_ws, size_t ws_size,
                              hipStream_t stream) {
  const float* enc = (const float*)d_in[0];   // encoder_out (targets)
  const float* qf  = (const float*)d_in[1];   // quantized_features (labels)
  const float* perp = (const float*)d_in[2];  // perplexity
  int N = in_sizes[0] / D_DIM;   // 4096
  int GV = in_sizes[2];          // 640

  float* ws = (float*)d_ws;
  float* rowloss = ws;                            // N floats
  uint32_t* counter = (uint32_t*)(ws + N);        // 1 dword ticket (+3 pad)
  uint32_t* tab = (uint32_t*)(ws + N + 4);        // N*192 dwords (fp8), 16B-aligned

  size_t needed = (size_t)(N + 4) * 4 + (size_t)N * D_DIM;
  if (ws_size >= needed) {
    prep_fp8_kernel<<<(N + 3) / 4, 256, 0, stream>>>(qf, tab, counter, N);
    contrast_fp8_kernel<<<N, 256, 0, stream>>>(enc, tab, perp, rowloss, counter,
                                               (float*)d_out, N, GV);
  } else {
    float* rt = ws + N;
    float* rl = ws + 2 * N;
    rnorm_kernel<<<(N + 3) / 4, 256, 0, stream>>>(enc, rt, N);
    rnorm_kernel<<<(N + 3) / 4, 256, 0, stream>>>(qf, rl, N);
    contrast_kernel<<<N, 256, 0, stream>>>(enc, qf, rt, rl, rowloss, N);
    finalize_kernel<<<1, 256, 0, stream>>>(rowloss, perp, (float*)d_out, N, GV);
  }
}

// Round 8
// 43.739 us; speedup vs baseline: 4.2934x; 4.2934x over previous
//
#include <hip/hip_runtime.h>
#include <stdint.h>

#define D_DIM 768
#define KNEG 100
#define INV_KAPPA 10.0f
#define FP8_SCALE 16.0f

typedef float floatx2 __attribute__((ext_vector_type(2)));

// ---------------- threefry2x32 (exact JAX semantics) ----------------
__device__ __forceinline__ uint32_t rotl32(uint32_t x, int r) {
  return (x << r) | (x >> (32 - r));
}

#define TF_R4(a, b, c, d)                        \
  x0 += x1; x1 = rotl32(x1, a); x1 ^= x0;        \
  x0 += x1; x1 = rotl32(x1, b); x1 ^= x0;        \
  x0 += x1; x1 = rotl32(x1, c); x1 ^= x0;        \
  x0 += x1; x1 = rotl32(x1, d); x1 ^= x0;

__device__ __forceinline__ void threefry2x32(uint32_t ks0, uint32_t ks1,
                                             uint32_t x0, uint32_t x1,
                                             uint32_t& o0, uint32_t& o1) {
  uint32_t ks2 = ks0 ^ ks1 ^ 0x1BD11BDAu;
  x0 += ks0; x1 += ks1;
  TF_R4(13, 15, 26, 6)   x0 += ks1; x1 += ks2 + 1u;
  TF_R4(17, 29, 16, 24)  x0 += ks2; x1 += ks0 + 2u;
  TF_R4(13, 15, 26, 6)   x0 += ks0; x1 += ks1 + 3u;
  TF_R4(17, 29, 16, 24)  x0 += ks1; x1 += ks2 + 4u;
  TF_R4(13, 15, 26, 6)   x0 += ks2; x1 += ks0 + 5u;
  o0 = x0; o1 = x1;
}

__device__ __forceinline__ int sample_negative(int row, int k, int N) {
  // replicate jax.random.randint(key(42), (N,100), 0, N-1) element (row,k)
  uint32_t a0, b0, a1, b1;
  threefry2x32(0u, 42u, 0u, 2u, a0, b0);   // constant-folds at -O3
  threefry2x32(0u, 42u, 1u, 3u, a1, b1);
  uint32_t total = (uint32_t)N * KNEG;
  uint32_t half = total >> 1;
  uint32_t j = (uint32_t)row * KNEG + (uint32_t)k;
  uint32_t x0 = (j < half) ? j : (j - half);
  uint32_t x1 = (j < half) ? (j + half) : j;
  uint32_t h0, h1, l0, l1;
  threefry2x32(a0, a1, x0, x1, h0, h1);
  threefry2x32(b0, b1, x0, x1, l0, l1);
  uint32_t hb = (j < half) ? h0 : h1;
  uint32_t lb = (j < half) ? l0 : l1;
  uint32_t span = (uint32_t)(N - 1);
  uint32_t mult = 65536u % span;
  mult = (mult * mult) % span;
  uint32_t off = ((hb % span) * mult + (lb % span)) % span;
  int idx = (int)off;
  if (idx >= row) idx++;  // skip self
  return idx;
}

// ---------------- fp8 encode/decode + packed f32 math (inline asm) ----------------
__device__ __forceinline__ uint32_t enc_fp8x2(float a, float b) {
  uint32_t r;
  asm volatile("v_cvt_pk_fp8_f32 %0, %1, %2" : "=v"(r) : "v"(a), "v"(b));
  return r;  // valid fp8 pair in [15:0]
}
__device__ __forceinline__ uint32_t enc_fp8x4(float a, float b, float c, float d) {
  uint32_t lo = enc_fp8x2(a, b);
  uint32_t hi = enc_fp8x2(c, d);
  return (lo & 0xFFFFu) | (hi << 16);
}
__device__ __forceinline__ floatx2 dec_fp8x2(uint32_t w) {
  floatx2 p;
  asm("v_cvt_pk_f32_fp8 %0, %1" : "=v"(p) : "v"(w));  // decodes bytes [1:0]
  return p;
}
__device__ __forceinline__ floatx2 pk_mul(floatx2 a, floatx2 b) {
  floatx2 d;
  asm("v_pk_mul_f32 %0, %1, %2" : "=v"(d) : "v"(a), "v"(b));
  return d;
}
__device__ __forceinline__ floatx2 pk_fma(floatx2 a, floatx2 b, floatx2 c) {
  floatx2 d;
  asm("v_pk_fma_f32 %0, %1, %2, %3" : "=v"(d) : "v"(a), "v"(b), "v"(c));
  return d;
}

// ---------------- reciprocal L2 norms (fallback path only) ----------------
__global__ __launch_bounds__(256) void rnorm_kernel(const float* __restrict__ x,
                                                    float* __restrict__ rn,
                                                    int nrows) {
  int wave = threadIdx.x >> 6;
  int lane = threadIdx.x & 63;
  int row = blockIdx.x * 4 + wave;
  if (row >= nrows) return;
  const float4* p = (const float4*)(x + (size_t)row * D_DIM);
  float s = 0.f;
#pragma unroll
  for (int q = 0; q < 3; ++q) {
    float4 v = p[lane + 64 * q];
    s += v.x * v.x + v.y * v.y + v.z * v.z + v.w * v.w;
  }
#pragma unroll
  for (int o = 32; o; o >>= 1) s += __shfl_xor(s, o);
  if (lane == 0) rn[row] = 1.0f / fmaxf(sqrtf(s), 1e-8f);
}

// ---------------- normalize labels -> fp8 table (x16), row = 192 dwords ----------------
__global__ __launch_bounds__(256) void prep_fp8_kernel(const float* __restrict__ lbl,
                                                       uint32_t* __restrict__ tab,
                                                       int nrows) {
  int wave = threadIdx.x >> 6;
  int lane = threadIdx.x & 63;
  int row = blockIdx.x * 4 + wave;
  if (row >= nrows) return;
  // element ownership mirrors the contrast kernel's target layout:
  //   elems 8L..8L+7 -> float4 [2L],[2L+1];  elems 512+4L..+3 -> float4 [128+L]
  const float4* p = (const float4*)(lbl + (size_t)row * D_DIM);
  float4 v0 = p[2 * lane], v1 = p[2 * lane + 1], v2 = p[128 + lane];
  float s = v0.x * v0.x + v0.y * v0.y + v0.z * v0.z + v0.w * v0.w +
            v1.x * v1.x + v1.y * v1.y + v1.z * v1.z + v1.w * v1.w +
            v2.x * v2.x + v2.y * v2.y + v2.z * v2.z + v2.w * v2.w;
#pragma unroll
  for (int o = 32; o; o >>= 1) s += __shfl_xor(s, o);
  float r = FP8_SCALE / fmaxf(sqrtf(s), 1e-8f);
  uint32_t d0 = enc_fp8x4(v0.x * r, v0.y * r, v0.z * r, v0.w * r);
  uint32_t d1 = enc_fp8x4(v1.x * r, v1.y * r, v1.z * r, v1.w * r);
  uint32_t d2 = enc_fp8x4(v2.x * r, v2.y * r, v2.z * r, v2.w * r);
  uint32_t* tp = tab + (size_t)row * (D_DIM / 4);
  ((uint2*)tp)[lane] = make_uint2(d0, d1);  // dwords 2L, 2L+1
  tp[128 + lane] = d2;                      // dword 128+L
}

// per-candidate fragment dot via packed-f32: 6 dec + 3 shr + 1 pk_mul + 5 pk_fma + 1 add
__device__ __forceinline__ float dot12_fp8(const floatx2 T[6], uint2 u, uint32_t w) {
  floatx2 acc = pk_mul(dec_fp8x2(u.x), T[0]);
  acc = pk_fma(dec_fp8x2(u.x >> 16), T[1], acc);
  acc = pk_fma(dec_fp8x2(u.y), T[2], acc);
  acc = pk_fma(dec_fp8x2(u.y >> 16), T[3], acc);
  acc = pk_fma(dec_fp8x2(w), T[4], acc);
  acc = pk_fma(dec_fp8x2(w >> 16), T[5], acc);
  return acc.x + acc.y;
}

__device__ __forceinline__ void load_b8(const uint32_t* __restrict__ tab,
                                        const int* cand, int base, int lane,
                                        uint2 u[8], uint32_t w[8]) {
#pragma unroll
  for (int i = 0; i < 8; ++i) {
    const uint32_t* p = tab + (size_t)cand[base + i] * (D_DIM / 4);
    u[i] = ((const uint2*)p)[lane];
    w[i] = p[128 + lane];
  }
}

__device__ __forceinline__ void dots_b8(const floatx2 T[6], const uint2 u[8],
                                        const uint32_t w[8], float s[8]) {
#pragma unroll
  for (int i = 0; i < 8; ++i) s[i] = dot12_fp8(T, u[i], w[i]);
}

// 8-value butterfly: 10 shuffles reduce 8 wave-wide accumulators;
// lane l<8 ends holding the total of accumulator l.
__device__ __forceinline__ void reduce8_store(const float s[8], float* sims,
                                              int base, int lane) {
  float x01 = (lane & 1) ? s[1] : s[0];
  float y01 = (lane & 1) ? s[0] : s[1];
  x01 += __shfl_xor(y01, 1);
  float x23 = (lane & 1) ? s[3] : s[2];
  float y23 = (lane & 1) ? s[2] : s[3];
  x23 += __shfl_xor(y23, 1);
  float x45 = (lane & 1) ? s[5] : s[4];
  float y45 = (lane & 1) ? s[4] : s[5];
  x45 += __shfl_xor(y45, 1);
  float x67 = (lane & 1) ? s[7] : s[6];
  float y67 = (lane & 1) ? s[6] : s[7];
  x67 += __shfl_xor(y67, 1);
  float p03 = (lane & 2) ? x23 : x01;
  float q03 = (lane & 2) ? x01 : x23;
  p03 += __shfl_xor(q03, 2);
  float p47 = (lane & 2) ? x67 : x45;
  float q47 = (lane & 2) ? x45 : x67;
  p47 += __shfl_xor(q47, 2);
  float r = (lane & 4) ? p47 : p03;
  float t = (lane & 4) ? p03 : p47;
  r += __shfl_xor(t, 4);
  r += __shfl_xor(r, 8);
  r += __shfl_xor(r, 16);
  r += __shfl_xor(r, 32);
  if (lane < 8) sims[base + lane] = r;
}

// ---------------- contrastive loss: fp8 gather, 2-deep pipelined 8-batches ----------------
__global__ __launch_bounds__(256) void contrast_fp8_kernel(
    const float* __restrict__ tgt, const uint32_t* __restrict__ tab,
    float* __restrict__ rowloss, int N) {
  int row = blockIdx.x;
  __shared__ int cand[104];
  __shared__ float sims[104];
  int tid = threadIdx.x;

  if (tid == 0) cand[0] = row;
  else if (tid <= KNEG) cand[tid] = sample_negative(row, tid - 1, N);
  else if (tid < 104) cand[tid] = row;  // pad: computed, never used by logsumexp
  __syncthreads();

  int wave = tid >> 6, lane = tid & 63;
  const float4* tp = (const float4*)(tgt + (size_t)row * D_DIM);
  float4 t0 = tp[2 * lane], t1 = tp[2 * lane + 1], t2 = tp[128 + lane];
  // per-wave target sumsq (replicated across waves; kills the rnorm pass)
  float ss = t0.x * t0.x + t0.y * t0.y + t0.z * t0.z + t0.w * t0.w +
             t1.x * t1.x + t1.y * t1.y + t1.z * t1.z + t1.w * t1.w +
             t2.x * t2.x + t2.y * t2.y + t2.z * t2.z + t2.w * t2.w;
#pragma unroll
  for (int o = 32; o; o >>= 1) ss += __shfl_xor(ss, o);
  float sc = (INV_KAPPA / FP8_SCALE) / fmaxf(sqrtf(ss), 1e-8f);
  floatx2 T[6];
  T[0] = floatx2{t0.x * sc, t0.y * sc};
  T[1] = floatx2{t0.z * sc, t0.w * sc};
  T[2] = floatx2{t1.x * sc, t1.y * sc};
  T[3] = floatx2{t1.z * sc, t1.w * sc};
  T[4] = floatx2{t2.x * sc, t2.y * sc};
  T[5] = floatx2{t2.z * sc, t2.w * sc};

  // wave w owns candidates [26w, 26w+26): batches 8/8/8/2, 2-deep pipeline.
  int cb = wave * 26;
  uint2 ua[8]; uint32_t wa[8];
  uint2 ub[8]; uint32_t wb[8];
  float s[8];

  load_b8(tab, cand, cb, lane, ua, wa);          // batch 0 in flight
  load_b8(tab, cand, cb + 8, lane, ub, wb);      // batch 1 in flight
  dots_b8(T, ua, wa, s);                         // consume batch 0
  reduce8_store(s, sims, cb, lane);
  load_b8(tab, cand, cb + 16, lane, ua, wa);     // batch 2 in flight
  dots_b8(T, ub, wb, s);                         // consume batch 1
  reduce8_store(s, sims, cb + 8, lane);
  // tail (2 candidates) in flight
  uint2 ut0, ut1; uint32_t wt0, wt1;
  {
    const uint32_t* p0 = tab + (size_t)cand[cb + 24] * (D_DIM / 4);
    const uint32_t* p1 = tab + (size_t)cand[cb + 25] * (D_DIM / 4);
    ut0 = ((const uint2*)p0)[lane]; wt0 = p0[128 + lane];
    ut1 = ((const uint2*)p1)[lane]; wt1 = p1[128 + lane];
  }
  dots_b8(T, ua, wa, s);                         // consume batch 2
  reduce8_store(s, sims, cb + 16, lane);
  {                                              // consume tail
    float s0 = dot12_fp8(T, ut0, wt0);
    float s1 = dot12_fp8(T, ut1, wt1);
    float x = (lane & 1) ? s1 : s0;
    float y = (lane & 1) ? s0 : s1;
    x += __shfl_xor(y, 1);
    x += __shfl_xor(x, 2);
    x += __shfl_xor(x, 4);
    x += __shfl_xor(x, 8);
    x += __shfl_xor(x, 16);
    x += __shfl_xor(x, 32);
    if (lane < 2) sims[cb + 24 + lane] = x;
  }
  __syncthreads();

  if (wave == 0) {
    float v0 = (lane < KNEG + 1) ? sims[lane] : -INFINITY;
    float v1 = (lane + 64 < KNEG + 1) ? sims[lane + 64] : -INFINITY;
    float m = fmaxf(v0, v1);
#pragma unroll
    for (int o = 32; o; o >>= 1) m = fmaxf(m, __shfl_xor(m, o));
    float e = ((lane < KNEG + 1) ? expf(v0 - m) : 0.f) +
              ((lane + 64 < KNEG + 1) ? expf(v1 - m) : 0.f);
#pragma unroll
    for (int o = 32; o; o >>= 1) e += __shfl_xor(e, o);
    if (lane == 0) rowloss[row] = m + logf(e) - sims[0];
  }
}

// ---------------- f32 fallback (tiny-ws safety; proven R0 path) ----------------
__global__ __launch_bounds__(256) void contrast_kernel(
    const float* __restrict__ tgt, const float* __restrict__ lbl,
    const float* __restrict__ rt, const float* __restrict__ rl,
    float* __restrict__ rowloss, int N) {
  int row = blockIdx.x;
  __shared__ int cand[104];
  __shared__ float sims[104];
  int tid = threadIdx.x;
  if (tid == 0) cand[0] = row;
  else if (tid <= KNEG) cand[tid] = sample_negative(row, tid - 1, N);
  __syncthreads();

  int wave = tid >> 6, lane = tid & 63;
  const float4* tp = (const float4*)(tgt + (size_t)row * D_DIM);
  float rscale = rt[row];
  float4 t0 = tp[lane], t1 = tp[lane + 64], t2 = tp[lane + 128];

  for (int c = wave; c < KNEG + 1; c += 4) {
    int ci = cand[c];
    const float4* lp = (const float4*)(lbl + (size_t)ci * D_DIM);
    float4 l0 = lp[lane], l1 = lp[lane + 64], l2 = lp[lane + 128];
    float s = t0.x * l0.x + t0.y * l0.y + t0.z * l0.z + t0.w * l0.w +
              t1.x * l1.x + t1.y * l1.y + t1.z * l1.z + t1.w * l1.w +
              t2.x * l2.x + t2.y * l2.y + t2.z * l2.z + t2.w * l2.w;
#pragma unroll
    for (int o = 32; o; o >>= 1) s += __shfl_xor(s, o);
    if (lane == 0) sims[c] = s * rscale * rl[ci] * INV_KAPPA;
  }
  __syncthreads();

  if (wave == 0) {
    float v0 = (lane < KNEG + 1) ? sims[lane] : -INFINITY;
    float v1 = (lane + 64 < KNEG + 1) ? sims[lane + 64] : -INFINITY;
    float m = fmaxf(v0, v1);
#pragma unroll
    for (int o = 32; o; o >>= 1) m = fmaxf(m, __shfl_xor(m, o));
    float e = ((lane < KNEG + 1) ? expf(v0 - m) : 0.f) +
              ((lane + 64 < KNEG + 1) ? expf(v1 - m) : 0.f);
#pragma unroll
    for (int o = 32; o; o >>= 1) e += __shfl_xor(e, o);
    if (lane == 0) rowloss[row] = m + logf(e) - sims[0];
  }
}

// ---------------- final deterministic reduction ----------------
__global__ __launch_bounds__(256) void finalize_kernel(
    const float* __restrict__ rowloss, const float* __restrict__ perp,
    float* __restrict__ out, int N, int GV) {
  int tid = threadIdx.x;
  float s = 0.f;
  for (int i = tid; i < N; i += 256) s += rowloss[i];
  float dv = 0.f;
  for (int i = tid; i < GV; i += 256) {
    float p = perp[i];
    dv += p * logf(p + 1e-9f);
  }
#pragma unroll
  for (int o = 32; o; o >>= 1) {
    s += __shfl_xor(s, o);
    dv += __shfl_xor(dv, o);
  }
  __shared__ float ss[4], sd[4];
  if ((tid & 63) == 0) { ss[tid >> 6] = s; sd[tid >> 6] = dv; }
  __syncthreads();
  if (tid == 0) {
    float S = ss[0] + ss[1] + ss[2] + ss[3];
    float DV = sd[0] + sd[1] + sd[2] + sd[3];
    out[0] = S / (float)N + 0.1f * (-DV / (float)GV);
  }
}

extern "C" void kernel_launch(void* const* d_in, const int* in_sizes, int n_in,
                              void* d_out, int out_size, void* d_ws, size_t ws_size,
                              hipStream_t stream) {
  const float* enc = (const float*)d_in[0];   // encoder_out (targets)
  const float* qf  = (const float*)d_in[1];   // quantized_features (labels)
  const float* perp = (const float*)d_in[2];  // perplexity
  int N = in_sizes[0] / D_DIM;   // 4096
  int GV = in_sizes[2];          // 640

  float* ws = (float*)d_ws;
  float* rowloss = ws;                        // N floats
  uint32_t* tab = (uint32_t*)(ws + N);        // N*192 dwords (fp8 table)

  size_t needed = (size_t)N * 4 + (size_t)N * D_DIM;
  if (ws_size >= needed) {
    prep_fp8_kernel<<<(N + 3) / 4, 256, 0, stream>>>(qf, tab, N);
    contrast_fp8_kernel<<<N, 256, 0, stream>>>(enc, tab, rowloss, N);
  } else {
    float* rt = ws + N;
    float* rl = ws + 2 * N;
    rnorm_kernel<<<(N + 3) / 4, 256, 0, stream>>>(enc, rt, N);
    rnorm_kernel<<<(N + 3) / 4, 256, 0, stream>>>(qf, rl, N);
    contrast_kernel<<<N, 256, 0, stream>>>(enc, qf, rt, rl, rowloss, N);
  }
  finalize_kernel<<<1, 256, 0, stream>>>(rowloss, perp, (float*)d_out, N, GV);
}

// Round 9
// 39.072 us; speedup vs baseline: 4.8063x; 1.1195x over previous
//
#include <hip/hip_runtime.h>
#include <stdint.h>

#define D_DIM 768
#define KNEG 100
#define INV_KAPPA 10.0f
#define Q_SCALE 127.0f

// ---------------- threefry2x32 (exact JAX semantics) ----------------
__device__ __forceinline__ uint32_t rotl32(uint32_t x, int r) {
  return (x << r) | (x >> (32 - r));
}

#define TF_R4(a, b, c, d)                        \
  x0 += x1; x1 = rotl32(x1, a); x1 ^= x0;        \
  x0 += x1; x1 = rotl32(x1, b); x1 ^= x0;        \
  x0 += x1; x1 = rotl32(x1, c); x1 ^= x0;        \
  x0 += x1; x1 = rotl32(x1, d); x1 ^= x0;

__device__ __forceinline__ void threefry2x32(uint32_t ks0, uint32_t ks1,
                                             uint32_t x0, uint32_t x1,
                                             uint32_t& o0, uint32_t& o1) {
  uint32_t ks2 = ks0 ^ ks1 ^ 0x1BD11BDAu;
  x0 += ks0; x1 += ks1;
  TF_R4(13, 15, 26, 6)   x0 += ks1; x1 += ks2 + 1u;
  TF_R4(17, 29, 16, 24)  x0 += ks2; x1 += ks0 + 2u;
  TF_R4(13, 15, 26, 6)   x0 += ks0; x1 += ks1 + 3u;
  TF_R4(17, 29, 16, 24)  x0 += ks1; x1 += ks2 + 4u;
  TF_R4(13, 15, 26, 6)   x0 += ks2; x1 += ks0 + 5u;
  o0 = x0; o1 = x1;
}

__device__ __forceinline__ int sample_negative(int row, int k, int N) {
  // replicate jax.random.randint(key(42), (N,100), 0, N-1) element (row,k)
  uint32_t a0, b0, a1, b1;
  threefry2x32(0u, 42u, 0u, 2u, a0, b0);   // constant-folds at -O3
  threefry2x32(0u, 42u, 1u, 3u, a1, b1);
  uint32_t total = (uint32_t)N * KNEG;
  uint32_t half = total >> 1;
  uint32_t j = (uint32_t)row * KNEG + (uint32_t)k;
  uint32_t x0 = (j < half) ? j : (j - half);
  uint32_t x1 = (j < half) ? (j + half) : j;
  uint32_t h0, h1, l0, l1;
  threefry2x32(a0, a1, x0, x1, h0, h1);
  threefry2x32(b0, b1, x0, x1, l0, l1);
  uint32_t hb = (j < half) ? h0 : h1;
  uint32_t lb = (j < half) ? l0 : l1;
  uint32_t span = (uint32_t)(N - 1);
  uint32_t mult = 65536u % span;
  mult = (mult * mult) % span;
  uint32_t off = ((hb % span) * mult + (lb % span)) % span;
  int idx = (int)off;
  if (idx >= row) idx++;  // skip self
  return idx;
}

// ---------------- i8 pack + hw dot4 (inline asm: assembles or build fails) ----------------
__device__ __forceinline__ uint32_t pack4_i8(float a, float b, float c, float d) {
  int ia = (int)rintf(a), ib = (int)rintf(b), ic = (int)rintf(c), id = (int)rintf(d);
  return (uint32_t)(ia & 255) | ((uint32_t)(ib & 255) << 8) |
         ((uint32_t)(ic & 255) << 16) | ((uint32_t)(id & 255) << 24);
}
// 12-elem i8 dot: 3 x v_dot4_i32_i8 (VOP3P, CDNA)
__device__ __forceinline__ int dot12_i8(uint32_t qt0, uint32_t qt1, uint32_t qt2,
                                        uint2 u, uint32_t w) {
  int acc = 0;
  asm("v_dot4_i32_i8 %0, %1, %2, %0" : "+v"(acc) : "v"(u.x), "v"(qt0));
  asm("v_dot4_i32_i8 %0, %1, %2, %0" : "+v"(acc) : "v"(u.y), "v"(qt1));
  asm("v_dot4_i32_i8 %0, %1, %2, %0" : "+v"(acc) : "v"(w),   "v"(qt2));
  return acc;
}

// ---------------- reciprocal L2 norms (fallback path only) ----------------
__global__ __launch_bounds__(256) void rnorm_kernel(const float* __restrict__ x,
                                                    float* __restrict__ rn,
                                                    int nrows) {
  int wave = threadIdx.x >> 6;
  int lane = threadIdx.x & 63;
  int row = blockIdx.x * 4 + wave;
  if (row >= nrows) return;
  const float4* p = (const float4*)(x + (size_t)row * D_DIM);
  float s = 0.f;
#pragma unroll
  for (int q = 0; q < 3; ++q) {
    float4 v = p[lane + 64 * q];
    s += v.x * v.x + v.y * v.y + v.z * v.z + v.w * v.w;
  }
#pragma unroll
  for (int o = 32; o; o >>= 1) s += __shfl_xor(s, o);
  if (lane == 0) rn[row] = 1.0f / fmaxf(sqrtf(s), 1e-8f);
}

// ---------------- normalize labels -> i8 table (x127), row = 192 dwords ----------------
__global__ __launch_bounds__(256) void prep_i8_kernel(const float* __restrict__ lbl,
                                                      uint32_t* __restrict__ tab,
                                                      int nrows) {
  int wave = threadIdx.x >> 6;
  int lane = threadIdx.x & 63;
  int row = blockIdx.x * 4 + wave;
  if (row >= nrows) return;
  // element ownership mirrors the contrast kernel's target layout:
  //   elems 8L..8L+7 -> float4 [2L],[2L+1];  elems 512+4L..+3 -> float4 [128+L]
  const float4* p = (const float4*)(lbl + (size_t)row * D_DIM);
  float4 v0 = p[2 * lane], v1 = p[2 * lane + 1], v2 = p[128 + lane];
  float s = v0.x * v0.x + v0.y * v0.y + v0.z * v0.z + v0.w * v0.w +
            v1.x * v1.x + v1.y * v1.y + v1.z * v1.z + v1.w * v1.w +
            v2.x * v2.x + v2.y * v2.y + v2.z * v2.z + v2.w * v2.w;
#pragma unroll
  for (int o = 32; o; o >>= 1) s += __shfl_xor(s, o);
  float r = Q_SCALE / fmaxf(sqrtf(s), 1e-8f);
  uint32_t d0 = pack4_i8(v0.x * r, v0.y * r, v0.z * r, v0.w * r);
  uint32_t d1 = pack4_i8(v1.x * r, v1.y * r, v1.z * r, v1.w * r);
  uint32_t d2 = pack4_i8(v2.x * r, v2.y * r, v2.z * r, v2.w * r);
  uint32_t* tp = tab + (size_t)row * (D_DIM / 4);
  ((uint2*)tp)[lane] = make_uint2(d0, d1);  // dwords 2L, 2L+1
  tp[128 + lane] = d2;                      // dword 128+L
}

__device__ __forceinline__ void load_b8(const uint32_t* __restrict__ tab,
                                        const int* cand, int base, int lane,
                                        uint2 u[8], uint32_t w[8]) {
#pragma unroll
  for (int i = 0; i < 8; ++i) {
    const uint32_t* p = tab + (size_t)cand[base + i] * (D_DIM / 4);
    u[i] = ((const uint2*)p)[lane];
    w[i] = p[128 + lane];
  }
}

__device__ __forceinline__ void dots_b8(uint32_t qt0, uint32_t qt1, uint32_t qt2,
                                        const uint2 u[8], const uint32_t w[8],
                                        int s[8]) {
#pragma unroll
  for (int i = 0; i < 8; ++i) s[i] = dot12_i8(qt0, qt1, qt2, u[i], w[i]);
}

// 8-value butterfly on i32 (exact): 10 shuffles reduce 8 wave-wide accumulators;
// lane l<8 ends holding the total of accumulator l; scaled once at store.
__device__ __forceinline__ void reduce8i_store(const int s[8], float* sims,
                                               int base, int lane, float ssc) {
  int x01 = (lane & 1) ? s[1] : s[0];
  int y01 = (lane & 1) ? s[0] : s[1];
  x01 += __shfl_xor(y01, 1);
  int x23 = (lane & 1) ? s[3] : s[2];
  int y23 = (lane & 1) ? s[2] : s[3];
  x23 += __shfl_xor(y23, 1);
  int x45 = (lane & 1) ? s[5] : s[4];
  int y45 = (lane & 1) ? s[4] : s[5];
  x45 += __shfl_xor(y45, 1);
  int x67 = (lane & 1) ? s[7] : s[6];
  int y67 = (lane & 1) ? s[6] : s[7];
  x67 += __shfl_xor(y67, 1);
  int p03 = (lane & 2) ? x23 : x01;
  int q03 = (lane & 2) ? x01 : x23;
  p03 += __shfl_xor(q03, 2);
  int p47 = (lane & 2) ? x67 : x45;
  int q47 = (lane & 2) ? x45 : x67;
  p47 += __shfl_xor(q47, 2);
  int r = (lane & 4) ? p47 : p03;
  int t = (lane & 4) ? p03 : p47;
  r += __shfl_xor(t, 4);
  r += __shfl_xor(r, 8);
  r += __shfl_xor(r, 16);
  r += __shfl_xor(r, 32);
  if (lane < 8) sims[base + lane] = (float)r * ssc;
}

// ---------------- contrastive loss: i8 gather, 2-deep pipelined 8-batches ----------------
__global__ __launch_bounds__(256) void contrast_i8_kernel(
    const float* __restrict__ tgt, const uint32_t* __restrict__ tab,
    float* __restrict__ rowloss, int N) {
  int row = blockIdx.x;
  __shared__ int cand[104];
  __shared__ float sims[104];
  int tid = threadIdx.x;

  if (tid == 0) cand[0] = row;
  else if (tid <= KNEG) cand[tid] = sample_negative(row, tid - 1, N);
  else if (tid < 104) cand[tid] = row;  // pad: computed, never used by logsumexp
  __syncthreads();

  int wave = tid >> 6, lane = tid & 63;
  const float4* tp = (const float4*)(tgt + (size_t)row * D_DIM);
  float4 t0 = tp[2 * lane], t1 = tp[2 * lane + 1], t2 = tp[128 + lane];
  // per-wave target sumsq (same ownership + reduce order as prep_i8 -> bitwise-equal quant)
  float ss = t0.x * t0.x + t0.y * t0.y + t0.z * t0.z + t0.w * t0.w +
             t1.x * t1.x + t1.y * t1.y + t1.z * t1.z + t1.w * t1.w +
             t2.x * t2.x + t2.y * t2.y + t2.z * t2.z + t2.w * t2.w;
#pragma unroll
  for (int o = 32; o; o >>= 1) ss += __shfl_xor(ss, o);
  float sc = Q_SCALE / fmaxf(sqrtf(ss), 1e-8f);
  uint32_t qt0 = pack4_i8(t0.x * sc, t0.y * sc, t0.z * sc, t0.w * sc);
  uint32_t qt1 = pack4_i8(t1.x * sc, t1.y * sc, t1.z * sc, t1.w * sc);
  uint32_t qt2 = pack4_i8(t2.x * sc, t2.y * sc, t2.z * sc, t2.w * sc);
  const float SSC = INV_KAPPA / (Q_SCALE * Q_SCALE);

  // wave w owns candidates [26w, 26w+26): batches 8/8/8/2, 2-deep pipeline.
  int cb = wave * 26;
  uint2 ua[8]; uint32_t wa[8];
  uint2 ub[8]; uint32_t wb[8];
  int s[8];

  load_b8(tab, cand, cb, lane, ua, wa);          // batch 0 in flight
  load_b8(tab, cand, cb + 8, lane, ub, wb);      // batch 1 in flight
  dots_b8(qt0, qt1, qt2, ua, wa, s);             // consume batch 0
  reduce8i_store(s, sims, cb, lane, SSC);
  load_b8(tab, cand, cb + 16, lane, ua, wa);     // batch 2 in flight
  dots_b8(qt0, qt1, qt2, ub, wb, s);             // consume batch 1
  reduce8i_store(s, sims, cb + 8, lane, SSC);
  // tail (2 candidates) in flight
  uint2 ut0, ut1; uint32_t wt0, wt1;
  {
    const uint32_t* p0 = tab + (size_t)cand[cb + 24] * (D_DIM / 4);
    const uint32_t* p1 = tab + (size_t)cand[cb + 25] * (D_DIM / 4);
    ut0 = ((const uint2*)p0)[lane]; wt0 = p0[128 + lane];
    ut1 = ((const uint2*)p1)[lane]; wt1 = p1[128 + lane];
  }
  dots_b8(qt0, qt1, qt2, ua, wa, s);             // consume batch 2
  reduce8i_store(s, sims, cb + 16, lane, SSC);
  {                                              // consume tail
    int s0 = dot12_i8(qt0, qt1, qt2, ut0, wt0);
    int s1 = dot12_i8(qt0, qt1, qt2, ut1, wt1);
    int x = (lane & 1) ? s1 : s0;
    int y = (lane & 1) ? s0 : s1;
    x += __shfl_xor(y, 1);
    x += __shfl_xor(x, 2);
    x += __shfl_xor(x, 4);
    x += __shfl_xor(x, 8);
    x += __shfl_xor(x, 16);
    x += __shfl_xor(x, 32);
    if (lane < 2) sims[cb + 24 + lane] = (float)x * SSC;
  }
  __syncthreads();

  if (wave == 0) {
    float v0 = (lane < KNEG + 1) ? sims[lane] : -INFINITY;
    float v1 = (lane + 64 < KNEG + 1) ? sims[lane + 64] : -INFINITY;
    float m = fmaxf(v0, v1);
#pragma unroll
    for (int o = 32; o; o >>= 1) m = fmaxf(m, __shfl_xor(m, o));
    float e = ((lane < KNEG + 1) ? expf(v0 - m) : 0.f) +
              ((lane + 64 < KNEG + 1) ? expf(v1 - m) : 0.f);
#pragma unroll
    for (int o = 32; o; o >>= 1) e += __shfl_xor(e, o);
    if (lane == 0) rowloss[row] = m + logf(e) - sims[0];
  }
}

// ---------------- f32 fallback (tiny-ws safety; proven R0 path) ----------------
__global__ __launch_bounds__(256) void contrast_kernel(
    const float* __restrict__ tgt, const float* __restrict__ lbl,
    const float* __restrict__ rt, const float* __restrict__ rl,
    float* __restrict__ rowloss, int N) {
  int row = blockIdx.x;
  __shared__ int cand[104];
  __shared__ float sims[104];
  int tid = threadIdx.x;
  if (tid == 0) cand[0] = row;
  else if (tid <= KNEG) cand[tid] = sample_negative(row, tid - 1, N);
  __syncthreads();

  int wave = tid >> 6, lane = tid & 63;
  const float4* tp = (const float4*)(tgt + (size_t)row * D_DIM);
  float rscale = rt[row];
  float4 t0 = tp[lane], t1 = tp[lane + 64], t2 = tp[lane + 128];

  for (int c = wave; c < KNEG + 1; c += 4) {
    int ci = cand[c];
    const float4* lp = (const float4*)(lbl + (size_t)ci * D_DIM);
    float4 l0 = lp[lane], l1 = lp[lane + 64], l2 = lp[lane + 128];
    float s = t0.x * l0.x + t0.y * l0.y + t0.z * l0.z + t0.w * l0.w +
              t1.x * l1.x + t1.y * l1.y + t1.z * l1.z + t1.w * l1.w +
              t2.x * l2.x + t2.y * l2.y + t2.z * l2.z + t2.w * l2.w;
#pragma unroll
    for (int o = 32; o; o >>= 1) s += __shfl_xor(s, o);
    if (lane == 0) sims[c] = s * rscale * rl[ci] * INV_KAPPA;
  }
  __syncthreads();

  if (wave == 0) {
    float v0 = (lane < KNEG + 1) ? sims[lane] : -INFINITY;
    float v1 = (lane + 64 < KNEG + 1) ? sims[lane + 64] : -INFINITY;
    float m = fmaxf(v0, v1);
#pragma unroll
    for (int o = 32; o; o >>= 1) m = fmaxf(m, __shfl_xor(m, o));
    float e = ((lane < KNEG + 1) ? expf(v0 - m) : 0.f) +
              ((lane + 64 < KNEG + 1) ? expf(v1 - m) : 0.f);
#pragma unroll
    for (int o = 32; o; o >>= 1) e += __shfl_xor(e, o);
    if (lane == 0) rowloss[row] = m + logf(e) - sims[0];
  }
}

// ---------------- final deterministic reduction ----------------
__global__ __launch_bounds__(256) void finalize_kernel(
    const float* __restrict__ rowloss, const float* __restrict__ perp,
    float* __restrict__ out, int N, int GV) {
  int tid = threadIdx.x;
  float s = 0.f;
  for (int i = tid; i < N; i += 256) s += rowloss[i];
  float dv = 0.f;
  for (int i = tid; i < GV; i += 256) {
    float p = perp[i];
    dv += p * logf(p + 1e-9f);
  }
#pragma unroll
  for (int o = 32; o; o >>= 1) {
    s += __shfl_xor(s, o);
    dv += __shfl_xor(dv, o);
  }
  __shared__ float ss[4], sd[4];
  if ((tid & 63) == 0) { ss[tid >> 6] = s; sd[tid >> 6] = dv; }
  __syncthreads();
  if (tid == 0) {
    float S = ss[0] + ss[1] + ss[2] + ss[3];
    float DV = sd[0] + sd[1] + sd[2] + sd[3];
    out[0] = S / (float)N + 0.1f * (-DV / (float)GV);
  }
}

extern "C" void kernel_launch(void* const* d_in, const int* in_sizes, int n_in,
                              void* d_out, int out_size, void* d_ws, size_t ws_size,
                              hipStream_t stream) {
  const float* enc = (const float*)d_in[0];   // encoder_out (targets)
  const float* qf  = (const float*)d_in[1];   // quantized_features (labels)
  const float* perp = (const float*)d_in[2];  // perplexity
  int N = in_sizes[0] / D_DIM;   // 4096
  int GV = in_sizes[2];          // 640

  float* ws = (float*)d_ws;
  float* rowloss = ws;                        // N floats
  uint32_t* tab = (uint32_t*)(ws + N);        // N*192 dwords (i8 table)

  size_t needed = (size_t)N * 4 + (size_t)N * D_DIM;
  if (ws_size >= needed) {
    prep_i8_kernel<<<(N + 3) / 4, 256, 0, stream>>>(qf, tab, N);
    contrast_i8_kernel<<<N, 256, 0, stream>>>(enc, tab, rowloss, N);
  } else {
    float* rt = ws + N;
    float* rl = ws + 2 * N;
    rnorm_kernel<<<(N + 3) / 4, 256, 0, stream>>>(enc, rt, N);
    rnorm_kernel<<<(N + 3) / 4, 256, 0, stream>>>(qf, rl, N);
    contrast_kernel<<<N, 256, 0, stream>>>(enc, qf, rt, rl, rowloss, N);
  }
  finalize_kernel<<<1, 256, 0, stream>>>(rowloss, perp, (float*)d_out, N, GV);
}

// Round 10
// 33.310 us; speedup vs baseline: 5.6376x; 1.1730x over previous
//
#include <hip/hip_runtime.h>
#include <stdint.h>

#define D_DIM 768
#define KNEG 100
#define INV_KAPPA 10.0f
#define RD4 96            // dwords per i4 row (768 * 4bit / 32)

// ---------------- threefry2x32 (exact JAX semantics) ----------------
__device__ __forceinline__ uint32_t rotl32(uint32_t x, int r) {
  return (x << r) | (x >> (32 - r));
}

#define TF_R4(a, b, c, d)                        \
  x0 += x1; x1 = rotl32(x1, a); x1 ^= x0;        \
  x0 += x1; x1 = rotl32(x1, b); x1 ^= x0;        \
  x0 += x1; x1 = rotl32(x1, c); x1 ^= x0;        \
  x0 += x1; x1 = rotl32(x1, d); x1 ^= x0;

__device__ __forceinline__ void threefry2x32(uint32_t ks0, uint32_t ks1,
                                             uint32_t x0, uint32_t x1,
                                             uint32_t& o0, uint32_t& o1) {
  uint32_t ks2 = ks0 ^ ks1 ^ 0x1BD11BDAu;
  x0 += ks0; x1 += ks1;
  TF_R4(13, 15, 26, 6)   x0 += ks1; x1 += ks2 + 1u;
  TF_R4(17, 29, 16, 24)  x0 += ks2; x1 += ks0 + 2u;
  TF_R4(13, 15, 26, 6)   x0 += ks0; x1 += ks1 + 3u;
  TF_R4(17, 29, 16, 24)  x0 += ks1; x1 += ks2 + 4u;
  TF_R4(13, 15, 26, 6)   x0 += ks2; x1 += ks0 + 5u;
  o0 = x0; o1 = x1;
}

__device__ __forceinline__ int sample_negative(int row, int k, int N) {
  // replicate jax.random.randint(key(42), (N,100), 0, N-1) element (row,k)
  uint32_t a0, b0, a1, b1;
  threefry2x32(0u, 42u, 0u, 2u, a0, b0);   // constant-folds at -O3
  threefry2x32(0u, 42u, 1u, 3u, a1, b1);
  uint32_t total = (uint32_t)N * KNEG;
  uint32_t half = total >> 1;
  uint32_t j = (uint32_t)row * KNEG + (uint32_t)k;
  uint32_t x0 = (j < half) ? j : (j - half);
  uint32_t x1 = (j < half) ? (j + half) : j;
  uint32_t h0, h1, l0, l1;
  threefry2x32(a0, a1, x0, x1, h0, h1);
  threefry2x32(b0, b1, x0, x1, l0, l1);
  uint32_t hb = (j < half) ? h0 : h1;
  uint32_t lb = (j < half) ? l0 : l1;
  uint32_t span = (uint32_t)(N - 1);
  uint32_t mult = 65536u % span;
  mult = (mult * mult) % span;
  uint32_t off = ((hb % span) * mult + (lb % span)) % span;
  int idx = (int)off;
  if (idx >= row) idx++;  // skip self
  return idx;
}

// ---------------- i4 pack + hw dot8 (inline asm: assembles or build fails) ----------------
__device__ __forceinline__ uint32_t pack8_i4(float4 a, float4 b, float f) {
  uint32_t d = 0;
  d |= ((uint32_t)((int)rintf(a.x * f) & 15));
  d |= ((uint32_t)((int)rintf(a.y * f) & 15)) << 4;
  d |= ((uint32_t)((int)rintf(a.z * f) & 15)) << 8;
  d |= ((uint32_t)((int)rintf(a.w * f) & 15)) << 12;
  d |= ((uint32_t)((int)rintf(b.x * f) & 15)) << 16;
  d |= ((uint32_t)((int)rintf(b.y * f) & 15)) << 20;
  d |= ((uint32_t)((int)rintf(b.z * f) & 15)) << 24;
  d |= ((uint32_t)((int)rintf(b.w * f) & 15)) << 28;
  return d;
}
__device__ __forceinline__ int dot24_i4(const uint32_t qt[3], const uint32_t d[3]) {
  int acc = 0;
  asm("v_dot8_i32_i4 %0, %1, %2, %0" : "+v"(acc) : "v"(d[0]), "v"(qt[0]));
  asm("v_dot8_i32_i4 %0, %1, %2, %0" : "+v"(acc) : "v"(d[1]), "v"(qt[1]));
  asm("v_dot8_i32_i4 %0, %1, %2, %0" : "+v"(acc) : "v"(d[2]), "v"(qt[2]));
  return acc;
}

// ---------------- reciprocal L2 norms (fallback path only) ----------------
__global__ __launch_bounds__(256) void rnorm_kernel(const float* __restrict__ x,
                                                    float* __restrict__ rn,
                                                    int nrows) {
  int wave = threadIdx.x >> 6;
  int lane = threadIdx.x & 63;
  int row = blockIdx.x * 4 + wave;
  if (row >= nrows) return;
  const float4* p = (const float4*)(x + (size_t)row * D_DIM);
  float s = 0.f;
#pragma unroll
  for (int q = 0; q < 3; ++q) {
    float4 v = p[lane + 64 * q];
    s += v.x * v.x + v.y * v.y + v.z * v.z + v.w * v.w;
  }
#pragma unroll
  for (int o = 32; o; o >>= 1) s += __shfl_xor(s, o);
  if (lane == 0) rn[row] = 1.0f / fmaxf(sqrtf(s), 1e-8f);
}

// ---------------- normalize labels -> i4 table (per-row scale), row = 96 dwords ----------------
__global__ __launch_bounds__(256) void prep_i4_kernel(const float* __restrict__ lbl,
                                                      uint32_t* __restrict__ tab,
                                                      float* __restrict__ tabscale,
                                                      int nrows) {
  int wave = threadIdx.x >> 6;
  int lane = threadIdx.x & 63;
  int row = blockIdx.x * 4 + wave;
  if (row >= nrows) return;
  const float4* p = (const float4*)(lbl + (size_t)row * D_DIM);
  float4 v0 = make_float4(0, 0, 0, 0), v1 = v0, v2 = v0, v3 = v0;
  float ss = 0.f, mx = 0.f;
  if (lane < 48) {  // lane owns elems [16*lane, 16*lane+16)
    v0 = p[4 * lane]; v1 = p[4 * lane + 1]; v2 = p[4 * lane + 2]; v3 = p[4 * lane + 3];
    ss = v0.x * v0.x + v0.y * v0.y + v0.z * v0.z + v0.w * v0.w +
         v1.x * v1.x + v1.y * v1.y + v1.z * v1.z + v1.w * v1.w +
         v2.x * v2.x + v2.y * v2.y + v2.z * v2.z + v2.w * v2.w +
         v3.x * v3.x + v3.y * v3.y + v3.z * v3.z + v3.w * v3.w;
    mx = fmaxf(fmaxf(fmaxf(fabsf(v0.x), fabsf(v0.y)), fmaxf(fabsf(v0.z), fabsf(v0.w))),
               fmaxf(fmaxf(fabsf(v1.x), fabsf(v1.y)), fmaxf(fabsf(v1.z), fabsf(v1.w))));
    mx = fmaxf(mx,
               fmaxf(fmaxf(fmaxf(fabsf(v2.x), fabsf(v2.y)), fmaxf(fabsf(v2.z), fabsf(v2.w))),
                     fmaxf(fmaxf(fabsf(v3.x), fabsf(v3.y)), fmaxf(fabsf(v3.z), fabsf(v3.w)))));
  }
#pragma unroll
  for (int o = 32; o; o >>= 1) {
    ss += __shfl_xor(ss, o);
    mx = fmaxf(mx, __shfl_xor(mx, o));
  }
  float n = fmaxf(sqrtf(ss), 1e-8f);
  float max_u = mx / n;
  float S = (max_u > 0.f) ? 7.0f / max_u : 0.f;
  float f = S / n;
  if (lane < 48) {
    uint32_t d0 = pack8_i4(v0, v1, f);
    uint32_t d1 = pack8_i4(v2, v3, f);
    ((uint2*)(tab + (size_t)row * RD4))[lane] = make_uint2(d0, d1);
  }
  if (lane == 0) tabscale[row] = max_u / 7.0f;  // = 1/S (0 for zero rows)
}

// ---------------- contrastive loss: i4 gather, pair-of-candidates per wave ----------------
__global__ __launch_bounds__(256) void contrast_i4_kernel(
    const float* __restrict__ tgt, const uint32_t* __restrict__ tab,
    const float* __restrict__ tabscale, float* __restrict__ rowloss, int N) {
  int row = blockIdx.x;
  __shared__ int cand[104];
  __shared__ float sims[104];
  __shared__ float sscale[104];
  int tid = threadIdx.x;

  if (tid == 0) {
    cand[0] = row; sscale[0] = tabscale[row];
  } else if (tid <= KNEG) {
    int c = sample_negative(row, tid - 1, N);
    cand[tid] = c; sscale[tid] = tabscale[c];
  } else if (tid < 104) {
    cand[tid] = row; sscale[tid] = tabscale[row];  // pad: computed, never read
  }
  __syncthreads();

  int wave = tid >> 6, lane = tid & 63;
  int hl = lane & 31, hsel = lane >> 5;  // half-lane, half-select (A/B candidate)

  // target fragment: dwords d = hl + 32*i (i=0..2); each half-wave holds the full row
  const float4* tp = (const float4*)(tgt + (size_t)row * D_DIM);
  float4 e0, e1, e2, e3, e4, e5;
  {
    int d0 = hl, d1 = hl + 32, d2 = hl + 64;
    e0 = tp[2 * d0]; e1 = tp[2 * d0 + 1];
    e2 = tp[2 * d1]; e3 = tp[2 * d1 + 1];
    e4 = tp[2 * d2]; e5 = tp[2 * d2 + 1];
  }
  float ss = e0.x * e0.x + e0.y * e0.y + e0.z * e0.z + e0.w * e0.w +
             e1.x * e1.x + e1.y * e1.y + e1.z * e1.z + e1.w * e1.w +
             e2.x * e2.x + e2.y * e2.y + e2.z * e2.z + e2.w * e2.w +
             e3.x * e3.x + e3.y * e3.y + e3.z * e3.z + e3.w * e3.w +
             e4.x * e4.x + e4.y * e4.y + e4.z * e4.z + e4.w * e4.w +
             e5.x * e5.x + e5.y * e5.y + e5.z * e5.z + e5.w * e5.w;
  float mx = 0.f;
  mx = fmaxf(mx, fmaxf(fmaxf(fabsf(e0.x), fabsf(e0.y)), fmaxf(fabsf(e0.z), fabsf(e0.w))));
  mx = fmaxf(mx, fmaxf(fmaxf(fabsf(e1.x), fabsf(e1.y)), fmaxf(fabsf(e1.z), fabsf(e1.w))));
  mx = fmaxf(mx, fmaxf(fmaxf(fabsf(e2.x), fabsf(e2.y)), fmaxf(fabsf(e2.z), fabsf(e2.w))));
  mx = fmaxf(mx, fmaxf(fmaxf(fabsf(e3.x), fabsf(e3.y)), fmaxf(fabsf(e3.z), fabsf(e3.w))));
  mx = fmaxf(mx, fmaxf(fmaxf(fabsf(e4.x), fabsf(e4.y)), fmaxf(fabsf(e4.z), fabsf(e4.w))));
  mx = fmaxf(mx, fmaxf(fmaxf(fabsf(e5.x), fabsf(e5.y)), fmaxf(fabsf(e5.z), fabsf(e5.w))));
#pragma unroll
  for (int o = 16; o; o >>= 1) {  // within 32-lane half (each half has the full row)
    ss += __shfl_xor(ss, o);
    mx = fmaxf(mx, __shfl_xor(mx, o));
  }
  float n = fmaxf(sqrtf(ss), 1e-8f);
  float max_u = mx / n;
  float S = (max_u > 0.f) ? 7.0f / max_u : 0.f;
  float f = S / n;
  uint32_t qt[3];
  qt[0] = pack8_i4(e0, e1, f);
  qt[1] = pack8_i4(e2, e3, f);
  qt[2] = pack8_i4(e4, e5, f);
  float scT = (max_u / 7.0f) * INV_KAPPA;  // invSt * 1/kappa (uniform per row)

  // wave owns candidates [26w, 26w+26) = 13 pairs; batches of 4/4/4/1 pairs.
  int cb = wave * 26;
  uint32_t A[4][3], B[4][3];
  int s4[4];

#define LOAD_PAIR(dst, pidx)                                         \
  {                                                                  \
    int ci = cand[cb + 2 * (pidx) + hsel];                           \
    const uint32_t* pp = tab + (size_t)ci * RD4;                     \
    dst[0] = pp[hl]; dst[1] = pp[hl + 32]; dst[2] = pp[hl + 64];     \
  }
#define LOAD_B4(dst, pb)                                             \
  LOAD_PAIR(dst[0], (pb) + 0) LOAD_PAIR(dst[1], (pb) + 1)            \
  LOAD_PAIR(dst[2], (pb) + 2) LOAD_PAIR(dst[3], (pb) + 3)
#define DOT_B4(src)                                                  \
  {                                                                  \
    s4[0] = dot24_i4(qt, src[0]); s4[1] = dot24_i4(qt, src[1]);      \
    s4[2] = dot24_i4(qt, src[2]); s4[3] = dot24_i4(qt, src[3]);      \
  }

  // multi-value butterfly within 32-lane half: 6 shuffles reduce 4 pairs;
  // lane hl<4 holds total of pair (hl) for its half.
#define RED_B4_STORE(pb)                                             \
  {                                                                  \
    int x01 = (hl & 1) ? s4[1] : s4[0];                              \
    int y01 = (hl & 1) ? s4[0] : s4[1];                              \
    x01 += __shfl_xor(y01, 1);                                       \
    int x23 = (hl & 1) ? s4[3] : s4[2];                              \
    int y23 = (hl & 1) ? s4[2] : s4[3];                              \
    x23 += __shfl_xor(y23, 1);                                       \
    int pr = (hl & 2) ? x23 : x01;                                   \
    int qr = (hl & 2) ? x01 : x23;                                   \
    pr += __shfl_xor(qr, 2);                                         \
    pr += __shfl_xor(pr, 4);                                         \
    pr += __shfl_xor(pr, 8);                                         \
    pr += __shfl_xor(pr, 16);                                        \
    if (hl < 4) {                                                    \
      int c = cb + 2 * ((pb) + hl) + hsel;                           \
      sims[c] = (float)pr * scT * sscale[c];                         \
    }                                                                \
  }

  LOAD_B4(A, 0)                       // pairs 0-3 in flight
  LOAD_B4(B, 4)                       // pairs 4-7 in flight
  DOT_B4(A) RED_B4_STORE(0)           // consume 0-3
  LOAD_B4(A, 8)                       // pairs 8-11 in flight
  DOT_B4(B) RED_B4_STORE(4)           // consume 4-7
  uint32_t T[3];
  LOAD_PAIR(T, 12)                    // tail pair in flight
  DOT_B4(A) RED_B4_STORE(8)           // consume 8-11
  {                                   // consume tail (pair 12: cands 24,25)
    int acc = dot24_i4(qt, T);
#pragma unroll
    for (int o = 16; o; o >>= 1) acc += __shfl_xor(acc, o);
    if (hl == 0) {
      int c = cb + 24 + hsel;
      sims[c] = (float)acc * scT * sscale[c];
    }
  }
#undef LOAD_PAIR
#undef LOAD_B4
#undef DOT_B4
#undef RED_B4_STORE
  __syncthreads();

  if (wave == 0) {
    float v0 = (lane < KNEG + 1) ? sims[lane] : -INFINITY;
    float v1 = (lane + 64 < KNEG + 1) ? sims[lane + 64] : -INFINITY;
    float m = fmaxf(v0, v1);
#pragma unroll
    for (int o = 32; o; o >>= 1) m = fmaxf(m, __shfl_xor(m, o));
    float e = ((lane < KNEG + 1) ? expf(v0 - m) : 0.f) +
              ((lane + 64 < KNEG + 1) ? expf(v1 - m) : 0.f);
#pragma unroll
    for (int o = 32; o; o >>= 1) e += __shfl_xor(e, o);
    if (lane == 0) rowloss[row] = m + logf(e) - sims[0];
  }
}

// ---------------- f32 fallback (tiny-ws safety; proven R0 path) ----------------
__global__ __launch_bounds__(256) void contrast_kernel(
    const float* __restrict__ tgt, const float* __restrict__ lbl,
    const float* __restrict__ rt, const float* __restrict__ rl,
    float* __restrict__ rowloss, int N) {
  int row = blockIdx.x;
  __shared__ int cand[104];
  __shared__ float sims[104];
  int tid = threadIdx.x;
  if (tid == 0) cand[0] = row;
  else if (tid <= KNEG) cand[tid] = sample_negative(row, tid - 1, N);
  __syncthreads();

  int wave = tid >> 6, lane = tid & 63;
  const float4* tp = (const float4*)(tgt + (size_t)row * D_DIM);
  float rscale = rt[row];
  float4 t0 = tp[lane], t1 = tp[lane + 64], t2 = tp[lane + 128];

  for (int c = wave; c < KNEG + 1; c += 4) {
    int ci = cand[c];
    const float4* lp = (const float4*)(lbl + (size_t)ci * D_DIM);
    float4 l0 = lp[lane], l1 = lp[lane + 64], l2 = lp[lane + 128];
    float s = t0.x * l0.x + t0.y * l0.y + t0.z * l0.z + t0.w * l0.w +
              t1.x * l1.x + t1.y * l1.y + t1.z * l1.z + t1.w * l1.w +
              t2.x * l2.x + t2.y * l2.y + t2.z * l2.z + t2.w * l2.w;
#pragma unroll
    for (int o = 32; o; o >>= 1) s += __shfl_xor(s, o);
    if (lane == 0) sims[c] = s * rscale * rl[ci] * INV_KAPPA;
  }
  __syncthreads();

  if (wave == 0) {
    float v0 = (lane < KNEG + 1) ? sims[lane] : -INFINITY;
    float v1 = (lane + 64 < KNEG + 1) ? sims[lane + 64] : -INFINITY;
    float m = fmaxf(v0, v1);
#pragma unroll
    for (int o = 32; o; o >>= 1) m = fmaxf(m, __shfl_xor(m, o));
    float e = ((lane < KNEG + 1) ? expf(v0 - m) : 0.f) +
              ((lane + 64 < KNEG + 1) ? expf(v1 - m) : 0.f);
#pragma unroll
    for (int o = 32; o; o >>= 1) e += __shfl_xor(e, o);
    if (lane == 0) rowloss[row] = m + logf(e) - sims[0];
  }
}

// ---------------- final deterministic reduction ----------------
__global__ __launch_bounds__(256) void finalize_kernel(
    const float* __restrict__ rowloss, const float* __restrict__ perp,
    float* __restrict__ out, int N, int GV) {
  int tid = threadIdx.x;
  float s = 0.f;
  for (int i = tid; i < N; i += 256) s += rowloss[i];
  float dv = 0.f;
  for (int i = tid; i < GV; i += 256) {
    float p = perp[i];
    dv += p * logf(p + 1e-9f);
  }
#pragma unroll
  for (int o = 32; o; o >>= 1) {
    s += __shfl_xor(s, o);
    dv += __shfl_xor(dv, o);
  }
  __shared__ float ss[4], sd[4];
  if ((tid & 63) == 0) { ss[tid >> 6] = s; sd[tid >> 6] = dv; }
  __syncthreads();
  if (tid == 0) {
    float S = ss[0] + ss[1] + ss[2] + ss[3];
    float DV = sd[0] + sd[1] + sd[2] + sd[3];
    out[0] = S / (float)N + 0.1f * (-DV / (float)GV);
  }
}

extern "C" void kernel_launch(void* const* d_in, const int* in_sizes, int n_in,
                              void* d_out, int out_size, void* d_ws, size_t ws_size,
                              hipStream_t stream) {
  const float* enc = (const float*)d_in[0];   // encoder_out (targets)
  const float* qf  = (const float*)d_in[1];   // quantized_features (labels)
  const float* perp = (const float*)d_in[2];  // perplexity
  int N = in_sizes[0] / D_DIM;   // 4096
  int GV = in_sizes[2];          // 640

  float* ws = (float*)d_ws;
  float* rowloss = ws;                        // N floats
  float* tabscale = ws + N;                   // N floats
  uint32_t* tab = (uint32_t*)(ws + 2 * N);    // N*96 dwords (i4 table)

  size_t needed = (size_t)2 * N * 4 + (size_t)N * RD4 * 4;
  if (ws_size >= needed) {
    prep_i4_kernel<<<(N + 3) / 4, 256, 0, stream>>>(qf, tab, tabscale, N);
    contrast_i4_kernel<<<N, 256, 0, stream>>>(enc, tab, tabscale, rowloss, N);
  } else {
    float* rt = ws + N;
    float* rl = ws + 2 * N;
    rnorm_kernel<<<(N + 3) / 4, 256, 0, stream>>>(enc, rt, N);
    rnorm_kernel<<<(N + 3) / 4, 256, 0, stream>>>(qf, rl, N);
    contrast_kernel<<<N, 256, 0, stream>>>(enc, qf, rt, rl, rowloss, N);
  }
  finalize_kernel<<<1, 256, 0, stream>>>(rowloss, perp, (float*)d_out, N, GV);
}